// Round 3
// baseline (317.561 us; speedup 1.0000x reference)
//
#include <hip/hip_runtime.h>
#include <stdint.h>

// Problem constants
#define Bsz 8
#define Cc  256
#define Crr 32
#define Nn  4096
#define CN  (Cc * Nn)

typedef unsigned short u16;
typedef __attribute__((ext_vector_type(8))) short  short8;
typedef __attribute__((ext_vector_type(4))) float  floatx4;
typedef __attribute__((ext_vector_type(4))) unsigned short u16x4;

__device__ __forceinline__ floatx4 mfma16(short8 a, short8 b, floatx4 c) {
  return __builtin_amdgcn_mfma_f32_16x16x32_bf16(a, b, c, 0, 0, 0);
}
__device__ __forceinline__ u16 f2bf(float f) {
  unsigned int u = __builtin_bit_cast(unsigned int, f);
  u = (u + 0x7FFFu + ((u >> 16) & 1u)) >> 16;   // RNE
  return (u16)u;
}
__device__ __forceinline__ float bf2f(u16 h) {
  unsigned int u = ((unsigned int)h) << 16;
  return __builtin_bit_cast(float, u);
}
// 8 consecutive fp32 -> bf16 fragment (two 16B loads)
__device__ __forceinline__ short8 pack8(const float* __restrict__ p) {
  floatx4 a = *(const floatx4*)p;
  floatx4 b = *(const floatx4*)(p + 4);
  short8 r;
  r[0] = (short)f2bf(a[0]); r[1] = (short)f2bf(a[1]);
  r[2] = (short)f2bf(a[2]); r[3] = (short)f2bf(a[3]);
  r[4] = (short)f2bf(b[0]); r[5] = (short)f2bf(b[1]);
  r[6] = (short)f2bf(b[2]); r[7] = (short)f2bf(b[3]);
  return r;
}
// 8 consecutive fp32 -> split bf16 (hi + lo) fragments
__device__ __forceinline__ void split8(const float* __restrict__ p,
                                       short8& hi, short8& lo) {
  floatx4 a = *(const floatx4*)p;
  floatx4 b = *(const floatx4*)(p + 4);
  float v[8] = {a[0], a[1], a[2], a[3], b[0], b[1], b[2], b[3]};
#pragma unroll
  for (int r = 0; r < 8; ++r) {
    u16 h = f2bf(v[r]);
    hi[r] = (short)h;
    lo[r] = (short)f2bf(v[r] - bf2f(h));
  }
}

// ---------------------------------------------------------------------------
// Kernel 1: projections f,g computed in split-bf16 precision (~fp32 accurate):
//   f = xh.wh + xh.wl + xl.wh  (missing xl.wl ~ 2^-18 rel), stored as split
//   bf16 pairs fThi/fTlo, gThi/gTlo in [N][32] frag-ready layout.
// Also emits bf16 w3 (always) and bf16 x copy (if ws allows).
// Block = (batch, 64-col n tile); x fragment is the shared MFMA A-operand.
// ---------------------------------------------------------------------------
template <bool XB16>
__launch_bounds__(256, 2)
__global__ void proj_kernel(const float* __restrict__ x,
                            const float* __restrict__ w1,
                            const float* __restrict__ w2,
                            const float* __restrict__ w3,
                            u16* __restrict__ w3b,
                            u16* __restrict__ fThi, u16* __restrict__ fTlo,
                            u16* __restrict__ gThi, u16* __restrict__ gTlo,
                            u16* __restrict__ xb) {
  const int bid = blockIdx.x;
  const int b   = bid & 7;          // batch pinned to XCD
  const int nt  = bid >> 3;
  const int tid  = threadIdx.x;
  const int w    = tid >> 6;
  const int lane = tid & 63;
  const int m    = lane & 15;
  const int q    = lane >> 4;
  const int nb   = nt * 64 + w * 16;

  const float* xsl = x + (size_t)b * CN;

  const floatx4 z4 = {0.f, 0.f, 0.f, 0.f};
  floatx4 aF[2] = {z4, z4}, aG[2] = {z4, z4};

  for (int c0 = 0; c0 < Cc; c0 += 32) {
    // x fragment, strided fp32 -> split bf16
    const float* xp = xsl + (size_t)(c0 + q * 8) * Nn + nb + m;
    short8 xh, xl;
#pragma unroll
    for (int r = 0; r < 8; ++r) {
      float v = xp[(size_t)r * Nn];
      u16 h = f2bf(v);
      xh[r] = (short)h;
      xl[r] = (short)f2bf(v - bf2f(h));
    }
    if (XB16) {
      u16* xo = xb + (size_t)b * CN + (size_t)(c0 + q * 8) * Nn + nb + m;
#pragma unroll
      for (int r = 0; r < 8; ++r) xo[(size_t)r * Nn] = (u16)xh[r];
    }
#pragma unroll
    for (int ot = 0; ot < 2; ++ot) {
      short8 wh, wl;
      split8(w1 + (size_t)(ot * 16 + m) * Cc + c0 + q * 8, wh, wl);
      aF[ot] = mfma16(xh, wh, aF[ot]);
      aF[ot] = mfma16(xh, wl, aF[ot]);
      aF[ot] = mfma16(xl, wh, aF[ot]);
      split8(w2 + (size_t)(ot * 16 + m) * Cc + c0 + q * 8, wh, wl);
      aG[ot] = mfma16(xh, wh, aG[ot]);
      aG[ot] = mfma16(xh, wl, aG[ot]);
      aG[ot] = mfma16(xl, wh, aG[ot]);
    }
  }
  // C/D: col = o (m), row = n (q*4+reg); store split pairs
#pragma unroll
  for (int ot = 0; ot < 2; ++ot)
#pragma unroll
    for (int r = 0; r < 4; ++r) {
      int n = nb + q * 4 + r;
      size_t idx = ((size_t)b * Nn + n) * Crr + ot * 16 + m;
      float vf = aF[ot][r];
      u16 hf = f2bf(vf);
      fThi[idx] = hf;
      fTlo[idx] = f2bf(vf - bf2f(hf));
      float vg = aG[ot][r];
      u16 hg = f2bf(vg);
      gThi[idx] = hg;
      gTlo[idx] = f2bf(vg - bf2f(hg));
    }
  // w3 -> bf16 (64 blocks x 1024 elements)
  if (bid < 64) {
    int base = bid * 1024 + tid * 4;
    floatx4 v = *(const floatx4*)(w3 + base);
    u16x4 o;
    o[0] = f2bf(v[0]); o[1] = f2bf(v[1]); o[2] = f2bf(v[2]); o[3] = f2bf(v[3]);
    *(u16x4*)(w3b + base) = o;
  }
}

// ---------------------------------------------------------------------------
// Kernel 2: streaming attention, y = x . softmax_cols(f^T g).
// Scores via split-bf16: s = fh.gh + fh.gl + fl.gh  (~fp32 accuracy).
// No max-subtraction: |s| <= ~40, exp stays in fp32/bf16 range; divide by l
// at the end. l is summed from the bf16-ROUNDED exp values so the P rounding
// is common-mode-cancelled by the normalization.
// Block = (batch, 64-j tile). Wave w: 16-i strip for S, 64-c strip for PV.
// P goes through LDS with a rotate swizzle on 16B granules (conflict-free).
// ---------------------------------------------------------------------------
template <bool XB16>
__launch_bounds__(256, 2)
__global__ void attn_kernel(const u16* __restrict__ fThi,
                            const u16* __restrict__ fTlo,
                            const u16* __restrict__ gThi,
                            const u16* __restrict__ gTlo,
                            const u16* __restrict__ xb,
                            const float* __restrict__ x,
                            float* __restrict__ y) {
  const int bid = blockIdx.x;
  const int b   = bid & 7;
  const int jt  = bid >> 3;
  const int j0  = jt * 64;
  const int tid  = threadIdx.x;
  const int w    = tid >> 6;
  const int lane = tid & 63;
  const int m    = lane & 15;
  const int q    = lane >> 4;

  __shared__ u16   P[64 * 64];
  __shared__ float lred[16 * 64];
  __shared__ float linv[64];

  const size_t fgb = (size_t)b * Nn * Crr;
  const u16*   xbs = xb + (size_t)b * CN;
  const float* xfs = x + (size_t)b * CN;

  short8 bgh[4], bgl[4];   // g fragments (loop-invariant): B[k=o][n=j]
#pragma unroll
  for (int jb = 0; jb < 4; ++jb) {
    size_t idx = fgb + (size_t)(j0 + jb * 16 + m) * Crr + q * 8;
    bgh[jb] = *(const short8*)(gThi + idx);
    bgl[jb] = *(const short8*)(gTlo + idx);
  }

  const floatx4 z4 = {0.f, 0.f, 0.f, 0.f};
  floatx4 acc[4][4];   // [cb][jb]: c = w*64+cb*16+q*4+r, j = j0+jb*16+m
#pragma unroll
  for (int cb = 0; cb < 4; ++cb)
#pragma unroll
    for (int jb = 0; jb < 4; ++jb) acc[cb][jb] = z4;

  float ps[4] = {0.f, 0.f, 0.f, 0.f};
  const int cbase = w * 64;
  const int wgran = 2 * w + (q >> 1);   // i/8 of this lane's S rows
  const int wsub  = (q & 1) * 4;        // i%8

  for (int it = 0; it < 64; ++it) {
    const int i0 = it * 64;

    // S strip: split-precision scores
    size_t fidx = fgb + (size_t)(i0 + w * 16 + m) * Crr + q * 8;
    short8 afh = *(const short8*)(fThi + fidx);
    short8 afl = *(const short8*)(fTlo + fidx);
    floatx4 sc[4];
#pragma unroll
    for (int jb = 0; jb < 4; ++jb) {
      floatx4 t = mfma16(afl, bgh[jb], z4);
      t = mfma16(afh, bgl[jb], t);
      sc[jb] = mfma16(afh, bgh[jb], t);
    }

    unsigned int pw[4][2];
#pragma unroll
    for (int jb = 0; jb < 4; ++jb) {
      u16 h0 = f2bf(__expf(sc[jb][0]));
      u16 h1 = f2bf(__expf(sc[jb][1]));
      u16 h2 = f2bf(__expf(sc[jb][2]));
      u16 h3 = f2bf(__expf(sc[jb][3]));
      // sum the ROUNDED values -> normalization cancels P's rounding bias
      ps[jb] += (bf2f(h0) + bf2f(h1)) + (bf2f(h2) + bf2f(h3));
      pw[jb][0] = (unsigned int)h0 | ((unsigned int)h1 << 16);
      pw[jb][1] = (unsigned int)h2 | ((unsigned int)h3 << 16);
    }

    __syncthreads();   // previous iteration's P readers done
#pragma unroll
    for (int jb = 0; jb < 4; ++jb) {
      int j = jb * 16 + m;
      int addr = j * 64 + ((wgran + j) & 7) * 8 + wsub;
      *(uint2*)(&P[addr]) = make_uint2(pw[jb][0], pw[jb][1]);
    }
    __syncthreads();   // P ready

    // PV: A = x (M=c, 64-row strip per wave), B = P from LDS
#pragma unroll
    for (int kk = 0; kk < 2; ++kk) {
      short8 bp[4];
#pragma unroll
      for (int jb = 0; jb < 4; ++jb) {
        int j = jb * 16 + m;
        int addr = j * 64 + (((kk * 4 + q) + j) & 7) * 8;
        bp[jb] = *(const short8*)(&P[addr]);
      }
#pragma unroll
      for (int cb = 0; cb < 4; ++cb) {
        short8 ah;
        if (XB16)
          ah = *(const short8*)(xbs + (size_t)(cbase + cb * 16 + m) * Nn +
                                i0 + kk * 32 + q * 8);
        else
          ah = pack8(xfs + (size_t)(cbase + cb * 16 + m) * Nn +
                     i0 + kk * 32 + q * 8);
#pragma unroll
        for (int jb = 0; jb < 4; ++jb)
          acc[cb][jb] = mfma16(ah, bp[jb], acc[cb][jb]);
      }
    }
  }

  // l reduction: 16 (wave,q) partials per j column
#pragma unroll
  for (int jb = 0; jb < 4; ++jb)
    lred[(w * 4 + q) * 64 + jb * 16 + m] = ps[jb];
  __syncthreads();
  if (tid < 64) {
    float s = 0.f;
#pragma unroll
    for (int t = 0; t < 16; ++t) s += lred[t * 64 + tid];
    linv[tid] = 1.0f / s;
  }
  __syncthreads();

  // y = O / l  (fp32, residual added later)
#pragma unroll
  for (int cb = 0; cb < 4; ++cb)
#pragma unroll
    for (int jb = 0; jb < 4; ++jb) {
      const int j  = j0 + jb * 16 + m;
      const float li = linv[jb * 16 + m];
#pragma unroll
      for (int r = 0; r < 4; ++r) {
        int c = cbase + cb * 16 + q * 4 + r;
        y[(size_t)(b * Cc + c) * Nn + j] = acc[cb][jb][r] * li;
      }
    }
}

// ---------------------------------------------------------------------------
// Kernel 3: out = w3 . y + x, in place on d_out (y lives there).
// Block = (batch, 64-j tile) reads only its own j-columns (all c), so the
// in-place hazard is intra-block only: all reads -> __syncthreads -> writes.
// ---------------------------------------------------------------------------
__launch_bounds__(256, 2)
__global__ void mix_kernel(const u16* __restrict__ w3b,
                           const float* __restrict__ x,
                           float* __restrict__ out) {
  const int bid = blockIdx.x;
  const int b   = bid & 7;
  const int jt  = bid >> 3;
  const int j0  = jt * 64;
  const int tid  = threadIdx.x;
  const int w    = tid >> 6;
  const int lane = tid & 63;
  const int m    = lane & 15;
  const int q    = lane >> 4;
  const int cbase = w * 64;

  const float* ysl = out + (size_t)b * CN;

  const floatx4 z4 = {0.f, 0.f, 0.f, 0.f};
  floatx4 acc[4][4];
#pragma unroll
  for (int ct = 0; ct < 4; ++ct)
#pragma unroll
    for (int jb = 0; jb < 4; ++jb) acc[ct][jb] = z4;

  for (int k0 = 0; k0 < Cc; k0 += 32) {
    short8 bf[4];   // B[k=c'][n=j] from y (strided fp32 -> bf16)
#pragma unroll
    for (int jb = 0; jb < 4; ++jb) {
      const float* yp = ysl + (size_t)(k0 + q * 8) * Nn + j0 + jb * 16 + m;
      short8 t;
#pragma unroll
      for (int r = 0; r < 8; ++r) t[r] = (short)f2bf(yp[(size_t)r * Nn]);
      bf[jb] = t;
    }
#pragma unroll
    for (int ct = 0; ct < 4; ++ct) {
      short8 aw = *(const short8*)(w3b + (size_t)(cbase + ct * 16 + m) * Cc +
                                   k0 + q * 8);
#pragma unroll
      for (int jb = 0; jb < 4; ++jb)
        acc[ct][jb] = mfma16(aw, bf[jb], acc[ct][jb]);
    }
  }

  __syncthreads();   // all y reads complete before in-place writes

  const float* xsl = x + (size_t)b * CN;
  float* osl = out + (size_t)b * CN;
#pragma unroll
  for (int ct = 0; ct < 4; ++ct)
#pragma unroll
    for (int jb = 0; jb < 4; ++jb)
#pragma unroll
      for (int r = 0; r < 4; ++r) {
        int c = cbase + ct * 16 + q * 4 + r;
        size_t idx = (size_t)c * Nn + j0 + jb * 16 + m;
        osl[idx] = acc[ct][jb][r] + xsl[idx];
      }
}

extern "C" void kernel_launch(void* const* d_in, const int* in_sizes, int n_in,
                              void* d_out, int out_size, void* d_ws, size_t ws_size,
                              hipStream_t stream) {
  const float* x  = (const float*)d_in[0];
  const float* w1 = (const float*)d_in[1];
  const float* w2 = (const float*)d_in[2];
  const float* w3 = (const float*)d_in[3];
  float* out = (float*)d_out;

  // ws layout (bf16 elements):
  //   w3b 64K | fThi 1M | fTlo 1M | gThi 1M | gTlo 1M | xb 8M (optional)
  const size_t FG = (size_t)Bsz * Nn * Crr;
  u16* w3b  = (u16*)d_ws;
  u16* fThi = w3b + (size_t)Cc * Cc;
  u16* fTlo = fThi + FG;
  u16* gThi = fTlo + FG;
  u16* gTlo = gThi + FG;
  u16* xb   = gTlo + FG;
  const size_t need_xb = ((size_t)Cc * Cc + 4 * FG + (size_t)Bsz * CN) * 2;
  const bool use_xb = ws_size >= need_xb;

  if (use_xb) {
    proj_kernel<true><<<dim3(512), dim3(256), 0, stream>>>(
        x, w1, w2, w3, w3b, fThi, fTlo, gThi, gTlo, xb);
    attn_kernel<true><<<dim3(512), dim3(256), 0, stream>>>(
        fThi, fTlo, gThi, gTlo, xb, x, out);
  } else {
    proj_kernel<false><<<dim3(512), dim3(256), 0, stream>>>(
        x, w1, w2, w3, w3b, fThi, fTlo, gThi, gTlo, xb);
    attn_kernel<false><<<dim3(512), dim3(256), 0, stream>>>(
        fThi, fTlo, gThi, gTlo, xb, x, out);
  }
  mix_kernel<<<dim3(512), dim3(256), 0, stream>>>(w3b, x, out);
}

// Round 4
// 230.599 us; speedup vs baseline: 1.3771x; 1.3771x over previous
//
#include <hip/hip_runtime.h>
#include <stdint.h>

// Problem constants
#define Bsz 8
#define Cc  256
#define Crr 32
#define Nn  4096
#define CN  (Cc * Nn)
#define ITILE 128
#define NIT (Nn / ITILE)   // 32

typedef unsigned short u16;
typedef __attribute__((ext_vector_type(8))) short  short8;
typedef __attribute__((ext_vector_type(4))) float  floatx4;
typedef __attribute__((ext_vector_type(4))) unsigned short u16x4;

__device__ __forceinline__ floatx4 mfma16(short8 a, short8 b, floatx4 c) {
  return __builtin_amdgcn_mfma_f32_16x16x32_bf16(a, b, c, 0, 0, 0);
}
__device__ __forceinline__ u16 f2bf(float f) {
  unsigned int u = __builtin_bit_cast(unsigned int, f);
  u = (u + 0x7FFFu + ((u >> 16) & 1u)) >> 16;   // RNE
  return (u16)u;
}
__device__ __forceinline__ float bf2f(u16 h) {
  unsigned int u = ((unsigned int)h) << 16;
  return __builtin_bit_cast(float, u);
}
__device__ __forceinline__ short8 pack8(const float* __restrict__ p) {
  floatx4 a = *(const floatx4*)p;
  floatx4 b = *(const floatx4*)(p + 4);
  short8 r;
  r[0] = (short)f2bf(a[0]); r[1] = (short)f2bf(a[1]);
  r[2] = (short)f2bf(a[2]); r[3] = (short)f2bf(a[3]);
  r[4] = (short)f2bf(b[0]); r[5] = (short)f2bf(b[1]);
  r[6] = (short)f2bf(b[2]); r[7] = (short)f2bf(b[3]);
  return r;
}
__device__ __forceinline__ void split8(const float* __restrict__ p,
                                       short8& hi, short8& lo) {
  floatx4 a = *(const floatx4*)p;
  floatx4 b = *(const floatx4*)(p + 4);
  float v[8] = {a[0], a[1], a[2], a[3], b[0], b[1], b[2], b[3]};
#pragma unroll
  for (int r = 0; r < 8; ++r) {
    u16 h = f2bf(v[r]);
    hi[r] = (short)h;
    lo[r] = (short)f2bf(v[r] - bf2f(h));
  }
}

// ---------------------------------------------------------------------------
// Kernel 1: projections f,g in split-bf16 (~fp32) precision, stored as split
// pairs in [N][32] frag-ready layout. x staged via LDS (coalesced global
// loads, 1 barrier/iter dbuf). Also emits bf16 w3 and (tier A) a TILED bf16
// x copy: per (i-tile of 32, c-tile of 16) a 1KB block in MFMA-A-fragment
// lane order, so attention's PV loads are single coalesced dwordx4.
// ---------------------------------------------------------------------------
template <bool XB16>
__launch_bounds__(256, 2)
__global__ void proj_kernel(const float* __restrict__ x,
                            const float* __restrict__ w1,
                            const float* __restrict__ w2,
                            const float* __restrict__ w3,
                            u16* __restrict__ w3b,
                            u16* __restrict__ fThi, u16* __restrict__ fTlo,
                            u16* __restrict__ gThi, u16* __restrict__ gTlo,
                            u16* __restrict__ xb) {
  const int bid = blockIdx.x;
  const int b   = bid & 7;          // batch pinned to XCD
  const int nt  = bid >> 3;
  const int tid  = threadIdx.x;
  const int w    = tid >> 6;
  const int lane = tid & 63;
  const int m    = lane & 15;
  const int q    = lane >> 4;
  const int nb0  = nt * 64;
  const int nb   = nb0 + w * 16;

  __shared__ float xs[2][32 * 66];   // row pad 66: conflict-free frag reads

  const float* xsl = x + (size_t)b * CN;
  const int srow = tid >> 3, scoff = (tid & 7) * 8;

  const floatx4 z4 = {0.f, 0.f, 0.f, 0.f};
  floatx4 aF[2] = {z4, z4}, aG[2] = {z4, z4};

  // stage c-chunk ci (32 rows x 64 cols fp32) into xs[ci&1]
  {
    const float* p = xsl + (size_t)(srow) * Nn + nb0 + scoff;
    floatx4 v0 = *(const floatx4*)p;
    floatx4 v1 = *(const floatx4*)(p + 4);
    float* d = &xs[0][srow * 66 + scoff];
    d[0]=v0[0]; d[1]=v0[1]; d[2]=v0[2]; d[3]=v0[3];
    d[4]=v1[0]; d[5]=v1[1]; d[6]=v1[2]; d[7]=v1[3];
  }

  for (int ci = 0; ci < 8; ++ci) {
    __syncthreads();
    if (ci + 1 < 8) {
      const float* p = xsl + (size_t)((ci + 1) * 32 + srow) * Nn + nb0 + scoff;
      floatx4 v0 = *(const floatx4*)p;
      floatx4 v1 = *(const floatx4*)(p + 4);
      float* d = &xs[(ci + 1) & 1][srow * 66 + scoff];
      d[0]=v0[0]; d[1]=v0[1]; d[2]=v0[2]; d[3]=v0[3];
      d[4]=v1[0]; d[5]=v1[1]; d[6]=v1[2]; d[7]=v1[3];
    }
    const float* xbuf = xs[ci & 1];
    const int c0 = ci * 32;
    short8 xh, xl;
#pragma unroll
    for (int r = 0; r < 8; ++r) {
      float v = xbuf[(q * 8 + r) * 66 + w * 16 + m];
      u16 h = f2bf(v);
      xh[r] = (short)h;
      xl[r] = (short)f2bf(v - bf2f(h));
    }
    if (XB16) {
      const int n  = nb + m;
      const int it = n >> 5;
      const int nq = ((n & 31) >> 3) << 4;
      const int el = n & 7;
      const size_t tb = (size_t)b * CN;
#pragma unroll
      for (int r = 0; r < 8; ++r) {
        int c = c0 + q * 8 + r;
        xb[tb + ((size_t)((it * 16 + (c >> 4)) << 9)) + ((c & 15) + nq) * 8 + el] =
            (u16)xh[r];
      }
    }
#pragma unroll
    for (int ot = 0; ot < 2; ++ot) {
      short8 wh, wl;
      split8(w1 + (size_t)(ot * 16 + m) * Cc + c0 + q * 8, wh, wl);
      aF[ot] = mfma16(xh, wh, aF[ot]);
      aF[ot] = mfma16(xh, wl, aF[ot]);
      aF[ot] = mfma16(xl, wh, aF[ot]);
      split8(w2 + (size_t)(ot * 16 + m) * Cc + c0 + q * 8, wh, wl);
      aG[ot] = mfma16(xh, wh, aG[ot]);
      aG[ot] = mfma16(xh, wl, aG[ot]);
      aG[ot] = mfma16(xl, wh, aG[ot]);
    }
  }

  // C/D: col = o (m), row = n (q*4+reg); store split pairs
#pragma unroll
  for (int ot = 0; ot < 2; ++ot)
#pragma unroll
    for (int r = 0; r < 4; ++r) {
      int n = nb + q * 4 + r;
      size_t idx = ((size_t)b * Nn + n) * Crr + ot * 16 + m;
      float vf = aF[ot][r];
      u16 hf = f2bf(vf);
      fThi[idx] = hf;
      fTlo[idx] = f2bf(vf - bf2f(hf));
      float vg = aG[ot][r];
      u16 hg = f2bf(vg);
      gThi[idx] = hg;
      gTlo[idx] = f2bf(vg - bf2f(hg));
    }
  // w3 -> bf16
  if (bid < 64) {
    int base = bid * 1024 + tid * 4;
    floatx4 v = *(const floatx4*)(w3 + base);
    u16x4 o;
    o[0] = f2bf(v[0]); o[1] = f2bf(v[1]); o[2] = f2bf(v[2]); o[3] = f2bf(v[3]);
    *(u16x4*)(w3b + base) = o;
  }
}

// ---------------------------------------------------------------------------
// Kernel 2: fused attention + channel-mix.
//   y = x . softmax_cols(f^T g);  out = w3 . y + x
// i-tile 128, double-buffered P, ONE barrier per iteration; S(t+1) computed
// between the barrier and PV(t) so exp/LDS latency hides under MFMA issue.
// P layout: rows j (64), 16B granules XOR-swizzled by (j&7): writes hit the
// b64 bank floor (4 dw/bank), reads the b128 floor (8 dw/bank).
// Epilogue: y^T (scaled by 1/l, bf16) goes into the P buffer, then a
// 256x256 w3 GEMM + residual writes out directly — no third kernel.
// ---------------------------------------------------------------------------
template <bool XB16>
__launch_bounds__(256, 2)
__global__ void attn_kernel(const u16* __restrict__ fThi,
                            const u16* __restrict__ fTlo,
                            const u16* __restrict__ gThi,
                            const u16* __restrict__ gTlo,
                            const u16* __restrict__ xb,
                            const float* __restrict__ x,
                            const u16* __restrict__ w3b,
                            float* __restrict__ out) {
  const int bid = blockIdx.x;
  const int b   = bid & 7;
  const int jt  = bid >> 3;
  const int j0  = jt * 64;
  const int tid  = threadIdx.x;
  const int w    = tid >> 6;
  const int lane = tid & 63;
  const int m    = lane & 15;
  const int q    = lane >> 4;

  __shared__ u16   P[2 * 64 * 128];   // 32 KB; reused as y^T in epilogue
  __shared__ float lred[16 * 64];
  __shared__ float linv[64];

  const size_t fgb = (size_t)b * (size_t)Nn * Crr;
  const u16*   xbs = xb + (size_t)b * CN;
  const float* xfs = x + (size_t)b * CN;

  short8 bgh[4], bgl[4];   // g fragments (loop-invariant): B[k=o][n=j]
#pragma unroll
  for (int jb = 0; jb < 4; ++jb) {
    size_t idx = fgb + (size_t)(j0 + jb * 16 + m) * Crr + q * 8;
    bgh[jb] = *(const short8*)(gThi + idx);
    bgl[jb] = *(const short8*)(gTlo + idx);
  }

  const floatx4 z4 = {0.f, 0.f, 0.f, 0.f};
  floatx4 acc[4][4];   // [cb][jb]: c = w*64+cb*16+q*4+r, j = j0+jb*16+m
#pragma unroll
  for (int cb = 0; cb < 4; ++cb)
#pragma unroll
    for (int jb = 0; jb < 4; ++jb) acc[cb][jb] = z4;

  float ps[4] = {0.f, 0.f, 0.f, 0.f};
  unsigned int pw[2][4][2];   // packed exp(S) for current tile
  const int iw = w * 32;      // wave's i-offset within the 128-tile
  const int cbase = w * 64;

  // compute S/exp/pack for tile t into pw (split-precision scores)
  auto computeS = [&](int t) {
#pragma unroll
    for (int isub = 0; isub < 2; ++isub) {
      const int ig = t * ITILE + iw + isub * 16 + m;
      size_t fidx = fgb + (size_t)ig * Crr + q * 8;
      short8 afh = *(const short8*)(fThi + fidx);
      short8 afl = *(const short8*)(fTlo + fidx);
#pragma unroll
      for (int jb = 0; jb < 4; ++jb) {
        floatx4 t3 = mfma16(afl, bgh[jb], z4);
        t3 = mfma16(afh, bgl[jb], t3);
        t3 = mfma16(afh, bgh[jb], t3);
        u16 h0 = f2bf(__expf(t3[0]));
        u16 h1 = f2bf(__expf(t3[1]));
        u16 h2 = f2bf(__expf(t3[2]));
        u16 h3 = f2bf(__expf(t3[3]));
        ps[jb] += (bf2f(h0) + bf2f(h1)) + (bf2f(h2) + bf2f(h3));
        pw[isub][jb][0] = (unsigned int)h0 | ((unsigned int)h1 << 16);
        pw[isub][jb][1] = (unsigned int)h2 | ((unsigned int)h3 << 16);
      }
    }
  };

  computeS(0);

  for (int t = 0; t < NIT; ++t) {
    u16* buf = P + (t & 1) * (64 * 128);
    // write P(t): granule g = i_loc/8, phys = g ^ (j&7); b64 at bank floor
#pragma unroll
    for (int isub = 0; isub < 2; ++isub) {
      const int g = w * 4 + isub * 2 + (q >> 1);
#pragma unroll
      for (int jb = 0; jb < 4; ++jb) {
        const int j = jb * 16 + m;
        const int ea = j * 128 + ((g ^ (j & 7)) * 8) + (q & 1) * 4;
        *(uint2*)(buf + ea) = make_uint2(pw[isub][jb][0], pw[isub][jb][1]);
      }
    }
    __syncthreads();

    // S(t+1) — scheduler interleaves this with PV(t) below
    if (t + 1 < NIT) computeS(t + 1);

    // PV(t): A = x tiles, B = P from LDS
#pragma unroll
    for (int kk = 0; kk < 4; ++kk) {
      short8 bp[4];
#pragma unroll
      for (int jb = 0; jb < 4; ++jb) {
        const int j = jb * 16 + m;
        const int g = kk * 4 + q;
        bp[jb] = *(const short8*)(buf + j * 128 + ((g ^ (j & 7)) * 8));
      }
#pragma unroll
      for (int cb = 0; cb < 4; ++cb) {
        short8 ah;
        if (XB16) {
          const int tile = (t * 4 + kk) * 16 + (w * 4 + cb);
          ah = *(const short8*)(xbs + ((size_t)tile << 9) + lane * 8);
        } else {
          ah = pack8(xfs + (size_t)(cbase + cb * 16 + m) * Nn +
                     t * ITILE + kk * 32 + q * 8);
        }
#pragma unroll
        for (int jb = 0; jb < 4; ++jb)
          acc[cb][jb] = mfma16(ah, bp[jb], acc[cb][jb]);
      }
    }
  }

  // ---- softmax denominator ----
#pragma unroll
  for (int jb = 0; jb < 4; ++jb)
    lred[(w * 4 + q) * 64 + jb * 16 + m] = ps[jb];
  __syncthreads();
  if (tid < 64) {
    float s = 0.f;
#pragma unroll
    for (int t = 0; t < 16; ++t) s += lred[t * 64 + tid];
    linv[tid] = 1.0f / s;
  }
  __syncthreads();

  // ---- y^T (scaled, bf16) into LDS: rows j (64) x 256 c, 16B-granule swizzle
  u16* yt = P;
#pragma unroll
  for (int cb = 0; cb < 4; ++cb)
#pragma unroll
    for (int jb = 0; jb < 4; ++jb) {
      const int j = jb * 16 + m;
      const float li = linv[j];
      const int g = w * 8 + cb * 2 + (q >> 1);
      const int ea = j * 256 + ((g ^ (j & 7)) * 8) + (q & 1) * 4;
      unsigned int d0 = (unsigned int)f2bf(acc[cb][jb][0] * li) |
                        ((unsigned int)f2bf(acc[cb][jb][1] * li) << 16);
      unsigned int d1 = (unsigned int)f2bf(acc[cb][jb][2] * li) |
                        ((unsigned int)f2bf(acc[cb][jb][3] * li) << 16);
      *(uint2*)(yt + ea) = make_uint2(d0, d1);
    }
  __syncthreads();

  // ---- channel mix: out = w3 . y + x
  floatx4 macc[4][4];
#pragma unroll
  for (int ct = 0; ct < 4; ++ct)
#pragma unroll
    for (int jb = 0; jb < 4; ++jb) macc[ct][jb] = z4;

  for (int k0 = 0; k0 < Cc; k0 += 32) {
    short8 bf[4];
#pragma unroll
    for (int jb = 0; jb < 4; ++jb) {
      const int j = jb * 16 + m;
      const int g = (k0 >> 3) + q;
      bf[jb] = *(const short8*)(yt + j * 256 + ((g ^ (j & 7)) * 8));
    }
#pragma unroll
    for (int ct = 0; ct < 4; ++ct) {
      short8 aw = *(const short8*)(w3b + (size_t)(cbase + ct * 16 + m) * Cc +
                                   k0 + q * 8);
#pragma unroll
      for (int jb = 0; jb < 4; ++jb)
        macc[ct][jb] = mfma16(aw, bf[jb], macc[ct][jb]);
    }
  }

  float* osl = out + (size_t)b * CN;
#pragma unroll
  for (int ct = 0; ct < 4; ++ct)
#pragma unroll
    for (int jb = 0; jb < 4; ++jb)
#pragma unroll
      for (int r = 0; r < 4; ++r) {
        const int c = cbase + ct * 16 + q * 4 + r;
        const size_t idx = (size_t)c * Nn + j0 + jb * 16 + m;
        osl[idx] = macc[ct][jb][r] + xfs[idx];
      }
}

extern "C" void kernel_launch(void* const* d_in, const int* in_sizes, int n_in,
                              void* d_out, int out_size, void* d_ws, size_t ws_size,
                              hipStream_t stream) {
  const float* x  = (const float*)d_in[0];
  const float* w1 = (const float*)d_in[1];
  const float* w2 = (const float*)d_in[2];
  const float* w3 = (const float*)d_in[3];
  float* out = (float*)d_out;

  // ws (bf16 elements): w3b 64K | fThi 1M | fTlo 1M | gThi 1M | gTlo 1M | xb 8M
  const size_t FG = (size_t)Bsz * Nn * Crr;
  u16* w3b  = (u16*)d_ws;
  u16* fThi = w3b + (size_t)Cc * Cc;
  u16* fTlo = fThi + FG;
  u16* gThi = fTlo + FG;
  u16* gTlo = gThi + FG;
  u16* xb   = gTlo + FG;
  const size_t need_xb = ((size_t)Cc * Cc + 4 * FG + (size_t)Bsz * CN) * 2;
  const bool use_xb = ws_size >= need_xb;

  if (use_xb) {
    proj_kernel<true><<<dim3(512), dim3(256), 0, stream>>>(
        x, w1, w2, w3, w3b, fThi, fTlo, gThi, gTlo, xb);
    attn_kernel<true><<<dim3(512), dim3(256), 0, stream>>>(
        fThi, fTlo, gThi, gTlo, xb, x, w3b, out);
  } else {
    proj_kernel<false><<<dim3(512), dim3(256), 0, stream>>>(
        x, w1, w2, w3, w3b, fThi, fTlo, gThi, gTlo, xb);
    attn_kernel<false><<<dim3(512), dim3(256), 0, stream>>>(
        fThi, fTlo, gThi, gTlo, xb, x, w3b, out);
  }
}